// Round 1
// 218.568 us; speedup vs baseline: 1.0096x; 1.0096x over previous
//
#include <hip/hip_runtime.h>
#include <stdint.h>

#define BATCH 4
#define CH 64
#define HW 80
#define NPIX 6400
#define SPLITS 3

typedef __attribute__((ext_vector_type(8))) short bf16x8;
typedef __attribute__((ext_vector_type(4))) float f32x4;

#define QSCALE 1.2011224087864498f   // sqrt(log2(e))
#define ESHIFT 115.41560327111707f   // 80 * log2(e)

static __device__ __forceinline__ unsigned short f2bf(float f) {
  union { float f; unsigned int u; } v; v.f = f;
  unsigned int u = v.u;
  return (unsigned short)((u + 0x7fffu + ((u >> 16) & 1u)) >> 16);
}
static __device__ __forceinline__ float bf2f(unsigned short h) {
  union { unsigned int u; float f; } v; v.u = ((unsigned int)h) << 16;
  return v.f;
}
// pack two floats to bf16x2 (round-half-up)
static __device__ __forceinline__ unsigned int pack2(float a, float b) {
  union { float f; unsigned int u; } x, y; x.f = a; y.f = b;
  return ((x.u + 0x8000u) >> 16) | ((y.u + 0x8000u) & 0xffff0000u);
}
// fp32 -> (hi bf16 | lo bf16 << 16)
static __device__ __forceinline__ unsigned int split_pack(float a) {
  unsigned short hi = f2bf(a);
  union { unsigned int u; float f; } hf; hf.u = ((unsigned int)hi) << 16;
  unsigned short lo = f2bf(a - hf.f);
  return (unsigned int)hi | ((unsigned int)lo << 16);
}

// ---------------- QKV 1x1 conv ----------------
__global__ __launch_bounds__(256) void qkv_kernel(
    const float* __restrict__ x, const float* __restrict__ w,
    const float* __restrict__ bias, unsigned short* __restrict__ Qtbf,
    unsigned short* __restrict__ Vbf, unsigned int* __restrict__ Kpk,
    unsigned int* __restrict__ Qpk) {
  __shared__ float qs[64][65];
  int bid = blockIdx.x;
  int b = bid / 100, tile = bid % 100;
  int p0 = tile * 64;
  int t = threadIdx.x;
  int i = t & 63;
  int og = __builtin_amdgcn_readfirstlane(t >> 6);
  int p = p0 + i;
  const float* xb = x + (size_t)b * CH * NPIX + p;
  float xv[64];
#pragma unroll
  for (int c = 0; c < 64; ++c) xv[c] = xb[(size_t)c * NPIX];
  size_t bc = (size_t)b * CH * NPIX;
  for (int j = 0; j < 48; ++j) {
    int o = og * 48 + j;
    const float* wr = w + o * 64;
    float a = bias[o];
#pragma unroll
    for (int c = 0; c < 64; ++c) a += wr[c] * xv[c];
    int cc = o & 63;
    int kind = o >> 6;
    if (kind == 0) {
      qs[cc][i] = a;
      Qpk[bc + (size_t)cc * NPIX + p] = split_pack(a);
    } else if (kind == 1) {
      Kpk[bc + (size_t)cc * NPIX + p] = split_pack(a);
    } else {
      Vbf[bc + (size_t)cc * NPIX + p] = f2bf(a);
    }
  }
  __syncthreads();
  // restage q -> Qtbf rows (row 128B contiguous, scaled by QSCALE)
  int j = t >> 2, g = t & 3;
  int pj = p0 + j;
  int tpj = (pj % HW) * HW + pj / HW;
  unsigned int pk8[8];
#pragma unroll
  for (int q4 = 0; q4 < 8; ++q4) {
    float a0 = qs[g * 16 + q4 * 2][j] * QSCALE;
    float a1 = qs[g * 16 + q4 * 2 + 1][j] * QSCALE;
    pk8[q4] = (unsigned int)f2bf(a0) | ((unsigned int)f2bf(a1) << 16);
  }
  unsigned short* dst = Qtbf + ((size_t)b * NPIX + tpj) * 64 + g * 16;
  uint4 w0 = {pk8[0], pk8[1], pk8[2], pk8[3]};
  uint4 w1 = {pk8[4], pk8[5], pk8[6], pk8[7]};
  *(uint4*)&dst[0] = w0;
  *(uint4*)&dst[8] = w1;
}

// ---------------- channel gram via split-bf16 MFMA ----------------
__global__ __launch_bounds__(256) void gram_kernel(
    const unsigned int* __restrict__ Kpk, const unsigned int* __restrict__ Qpk,
    float* __restrict__ Pc) {
  __shared__ unsigned short Ah[64 * 72], Al[64 * 72], Bh[64 * 72], Bl[64 * 72];
  int bid = blockIdx.x;
  int b = bid / 50, chunk = bid % 50;
  int t = threadIdx.x;
  int w = t >> 6, lane = t & 63;
  int quad = lane >> 4, l16 = lane & 15;
  size_t bc = (size_t)b * CH * NPIX;
  int row = t >> 2, g = t & 3;

  f32x4 acc[4];
#pragma unroll
  for (int ct = 0; ct < 4; ++ct) acc[ct] = (f32x4){0.f, 0.f, 0.f, 0.f};

  for (int sub = 0; sub < 2; ++sub) {
    int n0 = chunk * 128 + sub * 64;
    __syncthreads();
    const unsigned int* ks = Kpk + bc + (size_t)row * NPIX + n0 + g * 16;
#pragma unroll
    for (int q4 = 0; q4 < 4; ++q4) {
      uint4 u = *(const uint4*)&ks[q4 * 4];
      uint2 h = {(u.x & 0xffffu) | ((u.y & 0xffffu) << 16),
                 (u.z & 0xffffu) | ((u.w & 0xffffu) << 16)};
      uint2 l = {(u.x >> 16) | (u.y & 0xffff0000u),
                 (u.z >> 16) | (u.w & 0xffff0000u)};
      *(uint2*)&Ah[row * 72 + g * 16 + q4 * 4] = h;
      *(uint2*)&Al[row * 72 + g * 16 + q4 * 4] = l;
    }
    unsigned int qu[16];
#pragma unroll
    for (int ii = 0; ii < 16; ++ii) {
      int n = n0 + g * 16 + ii;
      int tn = (n % HW) * HW + n / HW;
      qu[ii] = Qpk[bc + (size_t)row * NPIX + tn];
    }
#pragma unroll
    for (int q4 = 0; q4 < 4; ++q4) {
      uint2 h = {(qu[q4 * 4] & 0xffffu) | ((qu[q4 * 4 + 1] & 0xffffu) << 16),
                 (qu[q4 * 4 + 2] & 0xffffu) | ((qu[q4 * 4 + 3] & 0xffffu) << 16)};
      uint2 l = {(qu[q4 * 4] >> 16) | (qu[q4 * 4 + 1] & 0xffff0000u),
                 (qu[q4 * 4 + 2] >> 16) | (qu[q4 * 4 + 3] & 0xffff0000u)};
      *(uint2*)&Bh[row * 72 + g * 16 + q4 * 4] = h;
      *(uint2*)&Bl[row * 72 + g * 16 + q4 * 4] = l;
    }
    __syncthreads();
#pragma unroll
    for (int ks2 = 0; ks2 < 2; ++ks2) {
      bf16x8 ah = *(const bf16x8*)&Ah[(w * 16 + l16) * 72 + ks2 * 32 + quad * 8];
      bf16x8 al = *(const bf16x8*)&Al[(w * 16 + l16) * 72 + ks2 * 32 + quad * 8];
#pragma unroll
      for (int ct = 0; ct < 4; ++ct) {
        bf16x8 bh = *(const bf16x8*)&Bh[(ct * 16 + l16) * 72 + ks2 * 32 + quad * 8];
        bf16x8 bl = *(const bf16x8*)&Bl[(ct * 16 + l16) * 72 + ks2 * 32 + quad * 8];
        acc[ct] = __builtin_amdgcn_mfma_f32_16x16x32_bf16(ah, bh, acc[ct], 0, 0, 0);
        acc[ct] = __builtin_amdgcn_mfma_f32_16x16x32_bf16(ah, bl, acc[ct], 0, 0, 0);
        acc[ct] = __builtin_amdgcn_mfma_f32_16x16x32_bf16(al, bh, acc[ct], 0, 0, 0);
      }
    }
  }
#pragma unroll
  for (int ct = 0; ct < 4; ++ct)
#pragma unroll
    for (int r = 0; r < 4; ++r)
      atomicAdd(&Pc[((size_t)b * 64 + w * 16 + quad * 4 + r) * 64 + ct * 16 + l16],
                acc[ct][r]);
}

// ---------------- flash spatial attention: split-K, no atomics, xor-swizzled LDS
// v2: query tile 128 -> 64 rows. Grid 600 -> 1200 blocks (4.7 blocks/CU),
// LDS 32KB -> 24KB (6 blocks/CU cap). Attacks the 18% occupancy limiter.
__global__ __launch_bounds__(256) void flash_kernel(
    const unsigned short* __restrict__ Qtbf, const unsigned short* __restrict__ Vbf,
    float* __restrict__ Opart, float* __restrict__ Lpart) {
  __shared__ char smem[24576] __attribute__((aligned(128)));
  unsigned short* Ks = (unsigned short*)smem;            // [64][64] swizzled
  unsigned short* Vs = (unsigned short*)(smem + 8192);   // [64][64] swizzled
  unsigned short* Pb = (unsigned short*)(smem + 16384);  // [64][64] swizzled (16 rows/wave)

  int bid = blockIdx.x;
  int b = bid / 300;
  int rem = bid % 300;
  int qt = rem / 3, split = rem % 3;
  int p0 = qt * 64;
  int t = threadIdx.x;
  int w = t >> 6, lane = t & 63;
  int quad = lane >> 4, l16 = lane & 15;
  int sw = l16 & 7;
  size_t bq = (size_t)b * NPIX;
  size_t bC = (size_t)b * CH * NPIX;

  // each wave owns 16 query rows: p0 + w*16 + l16
  bf16x8 aq[2];
#pragma unroll
  for (int ks = 0; ks < 2; ++ks)
    aq[ks] = *(const bf16x8*)&Qtbf[(bq + p0 + w * 16 + l16) * 64 + ks * 32 + quad * 8];

  f32x4 oacc[4];
#pragma unroll
  for (int ct = 0; ct < 4; ++ct) oacc[ct] = (f32x4){0.f, 0.f, 0.f, 0.f};
  float psum = 0.f;

  const unsigned short* Kb = Qtbf + bq * 64;
  const unsigned short* Vb = Vbf + bC;
  int r0 = t >> 3, s0 = t & 7;  // r0 in [0,32)
  int r1 = r0 + 32;
  int wOff0 = r0 * 64 + ((s0 ^ (r0 & 7)) << 3);  // swizzled LDS dest (halves)
  int wOff1 = r1 * 64 + ((s0 ^ (r1 & 7)) << 3);

  int kt0 = split * 34;
  int ktend = kt0 + ((split == 2) ? 32 : 34);

  uint4 kreg0, kreg1, vreg0, vreg1;
  {
    int n0 = kt0 * 64;
    kreg0 = *(const uint4*)&Kb[(size_t)(n0 + r0) * 64 + s0 * 8];
    vreg0 = *(const uint4*)&Vb[(size_t)r0 * NPIX + n0 + s0 * 8];
    kreg1 = *(const uint4*)&Kb[(size_t)(n0 + r1) * 64 + s0 * 8];
    vreg1 = *(const uint4*)&Vb[(size_t)r1 * NPIX + n0 + s0 * 8];
  }

  unsigned short* Pw = Pb + w * 16 * 64;
  for (int kt = kt0; kt < ktend; ++kt) {
    __syncthreads();  // prior iter's LDS reads done
    *(uint4*)&Ks[wOff0] = kreg0;
    *(uint4*)&Vs[wOff0] = vreg0;
    *(uint4*)&Ks[wOff1] = kreg1;
    *(uint4*)&Vs[wOff1] = vreg1;
    __syncthreads();
    if (kt + 1 < ktend) {
      int n1 = (kt + 1) * 64;
      kreg0 = *(const uint4*)&Kb[(size_t)(n1 + r0) * 64 + s0 * 8];
      vreg0 = *(const uint4*)&Vb[(size_t)r0 * NPIX + n1 + s0 * 8];
      kreg1 = *(const uint4*)&Kb[(size_t)(n1 + r1) * 64 + s0 * 8];
      vreg1 = *(const uint4*)&Vb[(size_t)r1 * NPIX + n1 + s0 * 8];
    }
    // S^T[k][m]: C-layout row=key=ct*16+quad*4+r, col=query=l16
    f32x4 sc[4];
#pragma unroll
    for (int ct = 0; ct < 4; ++ct) sc[ct] = (f32x4){0.f, 0.f, 0.f, 0.f};
#pragma unroll
    for (int ks = 0; ks < 2; ++ks)
#pragma unroll
      for (int ct = 0; ct < 4; ++ct) {
        bf16x8 bk = *(const bf16x8*)&Ks[(ct * 16 + l16) * 64 +
                                        (((ks * 4 + quad) ^ sw) << 3)];
        sc[ct] = __builtin_amdgcn_mfma_f32_16x16x32_bf16(bk, aq[ks], sc[ct], 0, 0, 0);
      }
    // exp2 + pack -> P[m][k] (swizzled)
#pragma unroll
    for (int ct = 0; ct < 4; ++ct) {
      float e0 = __builtin_amdgcn_exp2f(sc[ct][0] - ESHIFT);
      float e1 = __builtin_amdgcn_exp2f(sc[ct][1] - ESHIFT);
      float e2 = __builtin_amdgcn_exp2f(sc[ct][2] - ESHIFT);
      float e3 = __builtin_amdgcn_exp2f(sc[ct][3] - ESHIFT);
      psum += (e0 + e1) + (e2 + e3);
      uint2 pk = {pack2(e0, e1), pack2(e2, e3)};
      *(uint2*)&Pw[l16 * 64 +
                   (((2 * ct + (quad >> 1)) ^ sw) << 3) + ((quad & 1) << 2)] = pk;
    }
    bf16x8 pf[2];
#pragma unroll
    for (int ks = 0; ks < 2; ++ks)
      pf[ks] = *(const bf16x8*)&Pw[l16 * 64 + (((ks * 4 + quad) ^ sw) << 3)];
#pragma unroll
    for (int ks = 0; ks < 2; ++ks)
#pragma unroll
      for (int ct = 0; ct < 4; ++ct) {
        bf16x8 vf = *(const bf16x8*)&Vs[(ct * 16 + l16) * 64 +
                                        (((ks * 4 + quad) ^ sw) << 3)];
        oacc[ct] = __builtin_amdgcn_mfma_f32_16x16x32_bf16(vf, pf[ks], oacc[ct], 0, 0, 0);
      }
  }
  // epilogue: direct stores (no atomics)
  float* Op = Opart + (size_t)(split * BATCH + b) * CH * NPIX;
  int pcol = p0 + w * 16 + l16;
  {
    float s = psum;
    s += __shfl_xor(s, 16, 64);
    s += __shfl_xor(s, 32, 64);
    if (quad == 0) Lpart[(size_t)(split * BATCH + b) * NPIX + pcol] = s;
  }
#pragma unroll
  for (int ct = 0; ct < 4; ++ct)
#pragma unroll
    for (int r = 0; r < 4; ++r)
      Op[(size_t)(ct * 16 + quad * 4 + r) * NPIX + pcol] = oacc[ct][r];
}

// ---------------- finalize: out = chan_term + (sum_s Opart_s) / (sum_s Lpart_s)
__global__ __launch_bounds__(256) void finalize_kernel(
    const float* __restrict__ Pc, const unsigned short* __restrict__ Vbf,
    const float* __restrict__ Opart, const float* __restrict__ Lpart,
    float* __restrict__ out) {
  __shared__ float maT[64 * 64];  // [cp][c]
  int bid = blockIdx.x;
  int b = bid / 100, nt = bid % 100;
  int t = threadIdx.x;
  if (t < 64) {
    int c = t;
    const float* row = Pc + ((size_t)b * 64 + c) * 64;
    float v[64];
    float mx = -1e30f;
#pragma unroll
    for (int j = 0; j < 64; ++j) { v[j] = row[j]; mx = fmaxf(mx, v[j]); }
    float s = 0.f;
#pragma unroll
    for (int j = 0; j < 64; ++j) { v[j] = __expf(v[j] - mx); s += v[j]; }
    float inv = 1.f / s;
#pragma unroll
    for (int j = 0; j < 64; ++j) maT[j * 64 + c] = v[j] * inv;
  }
  __syncthreads();
  int lane = t & 63, ct = t >> 6;
  int n = nt * 64 + lane;
  size_t bc = (size_t)b * CH * NPIX;
  const unsigned short* vb = Vbf + bc + n;
  float acc[16];
#pragma unroll
  for (int j = 0; j < 16; ++j) acc[j] = 0.f;
  for (int cp = 0; cp < 64; ++cp) {
    float vv = bf2f(vb[(size_t)cp * NPIX]);
    const float* m = &maT[cp * 64 + ct * 16];
    f32x4 m0 = *(const f32x4*)&m[0];
    f32x4 m1 = *(const f32x4*)&m[4];
    f32x4 m2 = *(const f32x4*)&m[8];
    f32x4 m3 = *(const f32x4*)&m[12];
#pragma unroll
    for (int j = 0; j < 4; ++j) {
      acc[j] += m0[j] * vv;
      acc[4 + j] += m1[j] * vv;
      acc[8 + j] += m2[j] * vv;
      acc[12 + j] += m3[j] * vv;
    }
  }
  float lsum = Lpart[(size_t)(0 * BATCH + b) * NPIX + n] +
               Lpart[(size_t)(1 * BATCH + b) * NPIX + n] +
               Lpart[(size_t)(2 * BATCH + b) * NPIX + n];
  float inv = 1.f / lsum;
  const float* O0 = Opart + (size_t)(0 * BATCH + b) * CH * NPIX;
  const float* O1 = Opart + (size_t)(1 * BATCH + b) * CH * NPIX;
  const float* O2 = Opart + (size_t)(2 * BATCH + b) * CH * NPIX;
#pragma unroll
  for (int j = 0; j < 16; ++j) {
    size_t co = (size_t)(ct * 16 + j) * NPIX + n;
    float o = O0[co] + O1[co] + O2[co];
    out[bc + co] = acc[j] + o * inv;
  }
}

extern "C" void kernel_launch(void* const* d_in, const int* in_sizes, int n_in,
                              void* d_out, int out_size, void* d_ws, size_t ws_size,
                              hipStream_t stream) {
  const float* x = (const float*)d_in[0];
  const float* w = (const float*)d_in[1];
  const float* bias = (const float*)d_in[2];
  float* out = (float*)d_out;
  char* ws = (char*)d_ws;
  // layout (bytes):
  unsigned short* Qtbf = (unsigned short*)(ws);           // [0, 3276800)
  unsigned short* Vbf = (unsigned short*)(ws + 3276800);  // [3276800, 6553600)
  unsigned int* Kpk = (unsigned int*)(ws + 6553600);      // [6553600, 13107200) dead after gram
  unsigned int* Qpk = (unsigned int*)(ws + 13107200);     // [13107200, 19660800) dead after gram
  float* Opart = (float*)(ws + 6553600);                  // [6553600, 26214400) 3 splits, after gram
  float* Pc = (float*)(ws + 26214400);                    // [26214400, 26279936)
  float* Lpart = (float*)(ws + 26279936);                 // [26279936, 26587136)

  hipMemsetAsync(Pc, 0, 65536, stream);
  qkv_kernel<<<400, 256, 0, stream>>>(x, w, bias, Qtbf, Vbf, Kpk, Qpk);
  gram_kernel<<<200, 256, 0, stream>>>(Kpk, Qpk, Pc);
  flash_kernel<<<1200, 256, 0, stream>>>(Qtbf, Vbf, Opart, Lpart);
  finalize_kernel<<<400, 256, 0, stream>>>(Pc, Vbf, Opart, Lpart, out);
}

// Round 2
// 184.239 us; speedup vs baseline: 1.1977x; 1.1863x over previous
//
#include <hip/hip_runtime.h>
#include <stdint.h>

#define BATCH 4
#define CH 64
#define HW 80
#define NPIX 6400
#define SPLITS 3

typedef __attribute__((ext_vector_type(8))) short bf16x8;
typedef __attribute__((ext_vector_type(4))) float f32x4;

#define QSCALE 1.2011224087864498f   // sqrt(log2(e))
#define ESHIFT 115.41560327111707f   // 80 * log2(e)

static __device__ __forceinline__ unsigned short f2bf(float f) {
  union { float f; unsigned int u; } v; v.f = f;
  unsigned int u = v.u;
  return (unsigned short)((u + 0x7fffu + ((u >> 16) & 1u)) >> 16);
}
static __device__ __forceinline__ float bf2f(unsigned short h) {
  union { unsigned int u; float f; } v; v.u = ((unsigned int)h) << 16;
  return v.f;
}
// fp32 -> (hi bf16 | lo bf16 << 16)
static __device__ __forceinline__ unsigned int split_pack(float a) {
  unsigned short hi = f2bf(a);
  union { unsigned int u; float f; } hf; hf.u = ((unsigned int)hi) << 16;
  unsigned short lo = f2bf(a - hf.f);
  return (unsigned int)hi | ((unsigned int)lo << 16);
}
// de-interleave 8 split-packed uints (2x uint4) into hi/lo bf16x8 fragments
// packed word: low16 = hi-bf16, high16 = lo-bf16
static __device__ __forceinline__ void deint(uint4 a, uint4 b, bf16x8* h, bf16x8* l) {
  union { unsigned int u[4]; bf16x8 v; } H, L;
  H.u[0] = __builtin_amdgcn_perm(a.y, a.x, 0x05040100u);
  H.u[1] = __builtin_amdgcn_perm(a.w, a.z, 0x05040100u);
  H.u[2] = __builtin_amdgcn_perm(b.y, b.x, 0x05040100u);
  H.u[3] = __builtin_amdgcn_perm(b.w, b.z, 0x05040100u);
  L.u[0] = __builtin_amdgcn_perm(a.y, a.x, 0x07060302u);
  L.u[1] = __builtin_amdgcn_perm(a.w, a.z, 0x07060302u);
  L.u[2] = __builtin_amdgcn_perm(b.y, b.x, 0x07060302u);
  L.u[3] = __builtin_amdgcn_perm(b.w, b.z, 0x07060302u);
  *h = H.v; *l = L.v;
}

// ---------------- QKV 1x1 conv ----------------
// v3: 512 threads (8 output-groups x 24 outputs) - halves per-thread serial FMA
// chain, doubles waves/SIMD. Writes Qtn = Q at transposed pixel order so gram
// needs no scattered gathers.
__global__ __launch_bounds__(512) void qkv_kernel(
    const float* __restrict__ x, const float* __restrict__ w,
    const float* __restrict__ bias, unsigned short* __restrict__ Qtbf,
    unsigned short* __restrict__ Vbf, unsigned int* __restrict__ Kpk,
    unsigned int* __restrict__ Qtn) {
  __shared__ float qs[64][65];
  int bid = blockIdx.x;
  int b = bid / 100, tile = bid % 100;
  int p0 = tile * 64;
  int t = threadIdx.x;
  int i = t & 63;
  int og = __builtin_amdgcn_readfirstlane(t >> 6);  // 0..7
  int p = p0 + i;
  int tp = (p % HW) * HW + p / HW;  // involution transpose
  const float* xb = x + (size_t)b * CH * NPIX + p;
  float xv[64];
#pragma unroll
  for (int c = 0; c < 64; ++c) xv[c] = xb[(size_t)c * NPIX];
  size_t bc = (size_t)b * CH * NPIX;
  for (int j = 0; j < 24; ++j) {
    int o = og * 24 + j;
    const float* wr = w + o * 64;
    float a = bias[o];
#pragma unroll
    for (int c = 0; c < 64; ++c) a += wr[c] * xv[c];
    int cc = o & 63;
    int kind = o >> 6;
    if (kind == 0) {
      qs[cc][i] = a;
      // Qtn[c][n] = Q[c][tn(n)]  (scattered 4B store, stride 320B)
      Qtn[bc + (size_t)cc * NPIX + tp] = split_pack(a);
    } else if (kind == 1) {
      Kpk[bc + (size_t)cc * NPIX + p] = split_pack(a);
    } else {
      Vbf[bc + (size_t)cc * NPIX + p] = f2bf(a);
    }
  }
  __syncthreads();
  // restage q -> Qtbf rows (row 128B contiguous, scaled by QSCALE)
  int j2 = t >> 3, g = t & 7;  // j2 in [0,64), g in [0,8)
  int pj = p0 + j2;
  int tpj = (pj % HW) * HW + pj / HW;
  unsigned int pk4[4];
#pragma unroll
  for (int q4 = 0; q4 < 4; ++q4) {
    float a0 = qs[g * 8 + q4 * 2][j2] * QSCALE;
    float a1 = qs[g * 8 + q4 * 2 + 1][j2] * QSCALE;
    pk4[q4] = (unsigned int)f2bf(a0) | ((unsigned int)f2bf(a1) << 16);
  }
  unsigned short* dst = Qtbf + ((size_t)b * NPIX + tpj) * 64 + g * 8;
  uint4 w0 = {pk4[0], pk4[1], pk4[2], pk4[3]};
  *(uint4*)&dst[0] = w0;
}

// ---------------- channel gram via split-bf16 MFMA ----------------
// v3: both operands row-contiguous (Kpk, Qtn) -> no LDS, no scattered loads.
// Fragments built in-register via v_perm de-interleave. 400 blocks.
__global__ __launch_bounds__(256) void gram_kernel(
    const unsigned int* __restrict__ Kpk, const unsigned int* __restrict__ Qtn,
    float* __restrict__ Pc) {
  int bid = blockIdx.x;
  int b = bid / 100, chunk = bid % 100;
  int n0 = chunk * 64;
  int t = threadIdx.x;
  int w = t >> 6, lane = t & 63;
  int quad = lane >> 4, l16 = lane & 15;
  size_t bc = (size_t)b * CH * NPIX;

  f32x4 acc[4];
#pragma unroll
  for (int ct = 0; ct < 4; ++ct) acc[ct] = (f32x4){0.f, 0.f, 0.f, 0.f};

  // A-side (K): lane holds row w*16+l16, k-slices ks2*32 + quad*8
  const unsigned int* kp = Kpk + bc + (size_t)(w * 16 + l16) * NPIX + n0;
  bf16x8 ah[2], al[2];
#pragma unroll
  for (int ks2 = 0; ks2 < 2; ++ks2) {
    uint4 ua = *(const uint4*)&kp[ks2 * 32 + quad * 8];
    uint4 ub = *(const uint4*)&kp[ks2 * 32 + quad * 8 + 4];
    deint(ua, ub, &ah[ks2], &al[ks2]);
  }
#pragma unroll
  for (int ct = 0; ct < 4; ++ct) {
    const unsigned int* qp = Qtn + bc + (size_t)(ct * 16 + l16) * NPIX + n0;
#pragma unroll
    for (int ks2 = 0; ks2 < 2; ++ks2) {
      uint4 va = *(const uint4*)&qp[ks2 * 32 + quad * 8];
      uint4 vb = *(const uint4*)&qp[ks2 * 32 + quad * 8 + 4];
      bf16x8 bh, bl;
      deint(va, vb, &bh, &bl);
      acc[ct] = __builtin_amdgcn_mfma_f32_16x16x32_bf16(ah[ks2], bh, acc[ct], 0, 0, 0);
      acc[ct] = __builtin_amdgcn_mfma_f32_16x16x32_bf16(ah[ks2], bl, acc[ct], 0, 0, 0);
      acc[ct] = __builtin_amdgcn_mfma_f32_16x16x32_bf16(al[ks2], bh, acc[ct], 0, 0, 0);
    }
  }
#pragma unroll
  for (int ct = 0; ct < 4; ++ct)
#pragma unroll
    for (int r = 0; r < 4; ++r)
      atomicAdd(&Pc[((size_t)b * 64 + w * 16 + quad * 4 + r) * 64 + ct * 16 + l16],
                acc[ct][r]);
}

// ---------------- flash spatial attention: split-K, no atomics, xor-swizzled LDS
__global__ __launch_bounds__(256) void flash_kernel(
    const unsigned short* __restrict__ Qtbf, const unsigned short* __restrict__ Vbf,
    float* __restrict__ Opart, float* __restrict__ Lpart) {
  __shared__ char smem[24576] __attribute__((aligned(128)));
  unsigned short* Ks = (unsigned short*)smem;            // [64][64] swizzled
  unsigned short* Vs = (unsigned short*)(smem + 8192);   // [64][64] swizzled
  unsigned short* Pb = (unsigned short*)(smem + 16384);  // [64][64] swizzled (16 rows/wave)

  int bid = blockIdx.x;
  int b = bid / 300;
  int rem = bid % 300;
  int qt = rem / 3, split = rem % 3;
  int p0 = qt * 64;
  int t = threadIdx.x;
  int w = t >> 6, lane = t & 63;
  int quad = lane >> 4, l16 = lane & 15;
  int sw = l16 & 7;
  size_t bq = (size_t)b * NPIX;
  size_t bC = (size_t)b * CH * NPIX;

  // each wave owns 16 query rows: p0 + w*16 + l16
  bf16x8 aq[2];
#pragma unroll
  for (int ks = 0; ks < 2; ++ks)
    aq[ks] = *(const bf16x8*)&Qtbf[(bq + p0 + w * 16 + l16) * 64 + ks * 32 + quad * 8];

  f32x4 oacc[4];
#pragma unroll
  for (int ct = 0; ct < 4; ++ct) oacc[ct] = (f32x4){0.f, 0.f, 0.f, 0.f};
  float psum = 0.f;

  const unsigned short* Kb = Qtbf + bq * 64;
  const unsigned short* Vb = Vbf + bC;
  int r0 = t >> 3, s0 = t & 7;  // r0 in [0,32)
  int r1 = r0 + 32;
  int wOff0 = r0 * 64 + ((s0 ^ (r0 & 7)) << 3);  // swizzled LDS dest (halves)
  int wOff1 = r1 * 64 + ((s0 ^ (r1 & 7)) << 3);

  int kt0 = split * 34;
  int ktend = kt0 + ((split == 2) ? 32 : 34);

  uint4 kreg0, kreg1, vreg0, vreg1;
  {
    int n0 = kt0 * 64;
    kreg0 = *(const uint4*)&Kb[(size_t)(n0 + r0) * 64 + s0 * 8];
    vreg0 = *(const uint4*)&Vb[(size_t)r0 * NPIX + n0 + s0 * 8];
    kreg1 = *(const uint4*)&Kb[(size_t)(n0 + r1) * 64 + s0 * 8];
    vreg1 = *(const uint4*)&Vb[(size_t)r1 * NPIX + n0 + s0 * 8];
  }

  unsigned short* Pw = Pb + w * 16 * 64;
  for (int kt = kt0; kt < ktend; ++kt) {
    __syncthreads();  // prior iter's LDS reads done
    *(uint4*)&Ks[wOff0] = kreg0;
    *(uint4*)&Vs[wOff0] = vreg0;
    *(uint4*)&Ks[wOff1] = kreg1;
    *(uint4*)&Vs[wOff1] = vreg1;
    __syncthreads();
    if (kt + 1 < ktend) {
      int n1 = (kt + 1) * 64;
      kreg0 = *(const uint4*)&Kb[(size_t)(n1 + r0) * 64 + s0 * 8];
      vreg0 = *(const uint4*)&Vb[(size_t)r0 * NPIX + n1 + s0 * 8];
      kreg1 = *(const uint4*)&Kb[(size_t)(n1 + r1) * 64 + s0 * 8];
      vreg1 = *(const uint4*)&Vb[(size_t)r1 * NPIX + n1 + s0 * 8];
    }
    // S^T[k][m]: C-layout row=key=ct*16+quad*4+r, col=query=l16
    f32x4 sc[4];
#pragma unroll
    for (int ct = 0; ct < 4; ++ct) sc[ct] = (f32x4){0.f, 0.f, 0.f, 0.f};
#pragma unroll
    for (int ks = 0; ks < 2; ++ks)
#pragma unroll
      for (int ct = 0; ct < 4; ++ct) {
        bf16x8 bk = *(const bf16x8*)&Ks[(ct * 16 + l16) * 64 +
                                        (((ks * 4 + quad) ^ sw) << 3)];
        sc[ct] = __builtin_amdgcn_mfma_f32_16x16x32_bf16(bk, aq[ks], sc[ct], 0, 0, 0);
      }
    // exp2 + pack -> P[m][k] (swizzled); pack via v_cvt_pk_bf16_f32 (1 op vs 4)
#pragma unroll
    for (int ct = 0; ct < 4; ++ct) {
      float e0 = __builtin_amdgcn_exp2f(sc[ct][0] - ESHIFT);
      float e1 = __builtin_amdgcn_exp2f(sc[ct][1] - ESHIFT);
      float e2 = __builtin_amdgcn_exp2f(sc[ct][2] - ESHIFT);
      float e3 = __builtin_amdgcn_exp2f(sc[ct][3] - ESHIFT);
      psum += (e0 + e1) + (e2 + e3);
      unsigned int pk0, pk1;
      asm("v_cvt_pk_bf16_f32 %0, %1, %2" : "=v"(pk0) : "v"(e0), "v"(e1));
      asm("v_cvt_pk_bf16_f32 %0, %1, %2" : "=v"(pk1) : "v"(e2), "v"(e3));
      uint2 pk = {pk0, pk1};
      *(uint2*)&Pw[l16 * 64 +
                   (((2 * ct + (quad >> 1)) ^ sw) << 3) + ((quad & 1) << 2)] = pk;
    }
    bf16x8 pf[2];
#pragma unroll
    for (int ks = 0; ks < 2; ++ks)
      pf[ks] = *(const bf16x8*)&Pw[l16 * 64 + (((ks * 4 + quad) ^ sw) << 3)];
#pragma unroll
    for (int ks = 0; ks < 2; ++ks)
#pragma unroll
      for (int ct = 0; ct < 4; ++ct) {
        bf16x8 vf = *(const bf16x8*)&Vs[(ct * 16 + l16) * 64 +
                                        (((ks * 4 + quad) ^ sw) << 3)];
        oacc[ct] = __builtin_amdgcn_mfma_f32_16x16x32_bf16(vf, pf[ks], oacc[ct], 0, 0, 0);
      }
  }
  // epilogue: direct stores (no atomics)
  float* Op = Opart + (size_t)(split * BATCH + b) * CH * NPIX;
  int pcol = p0 + w * 16 + l16;
  {
    float s = psum;
    s += __shfl_xor(s, 16, 64);
    s += __shfl_xor(s, 32, 64);
    if (quad == 0) Lpart[(size_t)(split * BATCH + b) * NPIX + pcol] = s;
  }
#pragma unroll
  for (int ct = 0; ct < 4; ++ct)
#pragma unroll
    for (int r = 0; r < 4; ++r)
      Op[(size_t)(ct * 16 + quad * 4 + r) * NPIX + pcol] = oacc[ct][r];
}

// ---------------- finalize: out = chan_term + (sum_s Opart_s) / (sum_s Lpart_s)
__global__ __launch_bounds__(256) void finalize_kernel(
    const float* __restrict__ Pc, const unsigned short* __restrict__ Vbf,
    const float* __restrict__ Opart, const float* __restrict__ Lpart,
    float* __restrict__ out) {
  __shared__ float maT[64 * 64];  // [cp][c]
  int bid = blockIdx.x;
  int b = bid / 100, nt = bid % 100;
  int t = threadIdx.x;
  if (t < 64) {
    int c = t;
    const float* row = Pc + ((size_t)b * 64 + c) * 64;
    float v[64];
    float mx = -1e30f;
#pragma unroll
    for (int j = 0; j < 64; ++j) { v[j] = row[j]; mx = fmaxf(mx, v[j]); }
    float s = 0.f;
#pragma unroll
    for (int j = 0; j < 64; ++j) { v[j] = __expf(v[j] - mx); s += v[j]; }
    float inv = 1.f / s;
#pragma unroll
    for (int j = 0; j < 64; ++j) maT[j * 64 + c] = v[j] * inv;
  }
  __syncthreads();
  int lane = t & 63, ct = t >> 6;
  int n = nt * 64 + lane;
  size_t bc = (size_t)b * CH * NPIX;
  const unsigned short* vb = Vbf + bc + n;
  float acc[16];
#pragma unroll
  for (int j = 0; j < 16; ++j) acc[j] = 0.f;
  for (int cp = 0; cp < 64; ++cp) {
    float vv = bf2f(vb[(size_t)cp * NPIX]);
    const float* m = &maT[cp * 64 + ct * 16];
    f32x4 m0 = *(const f32x4*)&m[0];
    f32x4 m1 = *(const f32x4*)&m[4];
    f32x4 m2 = *(const f32x4*)&m[8];
    f32x4 m3 = *(const f32x4*)&m[12];
#pragma unroll
    for (int j = 0; j < 4; ++j) {
      acc[j] += m0[j] * vv;
      acc[4 + j] += m1[j] * vv;
      acc[8 + j] += m2[j] * vv;
      acc[12 + j] += m3[j] * vv;
    }
  }
  float lsum = Lpart[(size_t)(0 * BATCH + b) * NPIX + n] +
               Lpart[(size_t)(1 * BATCH + b) * NPIX + n] +
               Lpart[(size_t)(2 * BATCH + b) * NPIX + n];
  float inv = 1.f / lsum;
  const float* O0 = Opart + (size_t)(0 * BATCH + b) * CH * NPIX;
  const float* O1 = Opart + (size_t)(1 * BATCH + b) * CH * NPIX;
  const float* O2 = Opart + (size_t)(2 * BATCH + b) * CH * NPIX;
#pragma unroll
  for (int j = 0; j < 16; ++j) {
    size_t co = (size_t)(ct * 16 + j) * NPIX + n;
    float o = O0[co] + O1[co] + O2[co];
    out[bc + co] = acc[j] + o * inv;
  }
}

extern "C" void kernel_launch(void* const* d_in, const int* in_sizes, int n_in,
                              void* d_out, int out_size, void* d_ws, size_t ws_size,
                              hipStream_t stream) {
  const float* x = (const float*)d_in[0];
  const float* w = (const float*)d_in[1];
  const float* bias = (const float*)d_in[2];
  float* out = (float*)d_out;
  char* ws = (char*)d_ws;
  // layout (bytes):
  unsigned short* Qtbf = (unsigned short*)(ws);           // [0, 3276800)
  unsigned short* Vbf = (unsigned short*)(ws + 3276800);  // [3276800, 6553600)
  unsigned int* Kpk = (unsigned int*)(ws + 6553600);      // [6553600, 13107200) dead after gram
  unsigned int* Qtn = (unsigned int*)(ws + 13107200);     // [13107200, 19660800) dead after gram
  float* Opart = (float*)(ws + 6553600);                  // [6553600, 26214400) 3 splits, after gram
  float* Pc = (float*)(ws + 26214400);                    // [26214400, 26279936)
  float* Lpart = (float*)(ws + 26279936);                 // [26279936, 26587136)

  hipMemsetAsync(Pc, 0, 65536, stream);
  qkv_kernel<<<400, 512, 0, stream>>>(x, w, bias, Qtbf, Vbf, Kpk, Qtn);
  gram_kernel<<<400, 256, 0, stream>>>(Kpk, Qtn, Pc);
  flash_kernel<<<1200, 256, 0, stream>>>(Qtbf, Vbf, Opart, Lpart);
  finalize_kernel<<<400, 256, 0, stream>>>(Pc, Vbf, Opart, Lpart, out);
}

// Round 4
// 177.903 us; speedup vs baseline: 1.2403x; 1.0356x over previous
//
#include <hip/hip_runtime.h>
#include <stdint.h>

#define BATCH 4
#define CH 64
#define HW 80
#define NPIX 6400
#define SPLITS 3

typedef __attribute__((ext_vector_type(8))) short bf16x8;
typedef __attribute__((ext_vector_type(4))) float f32x4;

#define QSCALE 1.2011224087864498f   // sqrt(log2(e))
#define ESHIFT 115.41560327111707f   // 80 * log2(e)

static __device__ __forceinline__ unsigned short f2bf(float f) {
  union { float f; unsigned int u; } v; v.f = f;
  unsigned int u = v.u;
  return (unsigned short)((u + 0x7fffu + ((u >> 16) & 1u)) >> 16);
}
static __device__ __forceinline__ float bf2f(unsigned short h) {
  union { unsigned int u; float f; } v; v.u = ((unsigned int)h) << 16;
  return v.f;
}
// fp32 -> (hi bf16 | lo bf16 << 16)
static __device__ __forceinline__ unsigned int split_pack(float a) {
  unsigned short hi = f2bf(a);
  union { unsigned int u; float f; } hf; hf.u = ((unsigned int)hi) << 16;
  unsigned short lo = f2bf(a - hf.f);
  return (unsigned int)hi | ((unsigned int)lo << 16);
}
// de-interleave 8 split-packed uints (2x uint4) into hi/lo bf16x8 fragments
// packed word: low16 = hi-bf16, high16 = lo-bf16
static __device__ __forceinline__ void deint(uint4 a, uint4 b, bf16x8* h, bf16x8* l) {
  union { unsigned int u[4]; bf16x8 v; } H, L;
  H.u[0] = __builtin_amdgcn_perm(a.y, a.x, 0x05040100u);
  H.u[1] = __builtin_amdgcn_perm(a.w, a.z, 0x05040100u);
  H.u[2] = __builtin_amdgcn_perm(b.y, b.x, 0x05040100u);
  H.u[3] = __builtin_amdgcn_perm(b.w, b.z, 0x05040100u);
  L.u[0] = __builtin_amdgcn_perm(a.y, a.x, 0x07060302u);
  L.u[1] = __builtin_amdgcn_perm(a.w, a.z, 0x07060302u);
  L.u[2] = __builtin_amdgcn_perm(b.y, b.x, 0x07060302u);
  L.u[3] = __builtin_amdgcn_perm(b.w, b.z, 0x07060302u);
  *h = H.v; *l = L.v;
}

// ---------------- QKV 1x1 conv ----------------
// 4 concurrent accumulator chains (same per-output c-order -> bit-identical).
__global__ __launch_bounds__(512) void qkv_kernel(
    const float* __restrict__ x, const float* __restrict__ w,
    const float* __restrict__ bias, unsigned short* __restrict__ Qtbf,
    unsigned short* __restrict__ Vbf, unsigned int* __restrict__ Kpk,
    unsigned int* __restrict__ Qtn) {
  __shared__ float qs[64][65];
  int bid = blockIdx.x;
  int b = bid / 100, tile = bid % 100;
  int p0 = tile * 64;
  int t = threadIdx.x;
  int i = t & 63;
  int og = __builtin_amdgcn_readfirstlane(t >> 6);  // 0..7
  int p = p0 + i;
  int tp = (p % HW) * HW + p / HW;  // involution transpose
  const float* xb = x + (size_t)b * CH * NPIX + p;
  float xv[64];
#pragma unroll
  for (int c = 0; c < 64; ++c) xv[c] = xb[(size_t)c * NPIX];
  size_t bc = (size_t)b * CH * NPIX;
  for (int j = 0; j < 24; j += 4) {
    int o = og * 24 + j;
    const float* wr0 = w + o * 64;
    const float* wr1 = wr0 + 64;
    const float* wr2 = wr0 + 128;
    const float* wr3 = wr0 + 192;
    float a0 = bias[o], a1 = bias[o + 1], a2 = bias[o + 2], a3 = bias[o + 3];
#pragma unroll
    for (int c = 0; c < 64; ++c) {
      float xc = xv[c];
      a0 += wr0[c] * xc;
      a1 += wr1[c] * xc;
      a2 += wr2[c] * xc;
      a3 += wr3[c] * xc;
    }
    float av[4] = {a0, a1, a2, a3};
#pragma unroll
    for (int u = 0; u < 4; ++u) {
      int oo = o + u;
      int cc = oo & 63;
      int kind = oo >> 6;
      float a = av[u];
      if (kind == 0) {
        qs[cc][i] = a;
        // Qtn[c][n] = Q[c][tn(n)]  (scattered 4B store, stride 320B)
        Qtn[bc + (size_t)cc * NPIX + tp] = split_pack(a);
      } else if (kind == 1) {
        Kpk[bc + (size_t)cc * NPIX + p] = split_pack(a);
      } else {
        Vbf[bc + (size_t)cc * NPIX + p] = f2bf(a);
      }
    }
  }
  __syncthreads();
  // restage q -> Qtbf rows (row 128B contiguous, scaled by QSCALE)
  int j2 = t >> 3, g = t & 7;  // j2 in [0,64), g in [0,8)
  int pj = p0 + j2;
  int tpj = (pj % HW) * HW + pj / HW;
  unsigned int pk4[4];
#pragma unroll
  for (int q4 = 0; q4 < 4; ++q4) {
    float a0 = qs[g * 8 + q4 * 2][j2] * QSCALE;
    float a1 = qs[g * 8 + q4 * 2 + 1][j2] * QSCALE;
    pk4[q4] = (unsigned int)f2bf(a0) | ((unsigned int)f2bf(a1) << 16);
  }
  unsigned short* dst = Qtbf + ((size_t)b * NPIX + tpj) * 64 + g * 8;
  uint4 w0 = {pk4[0], pk4[1], pk4[2], pk4[3]};
  *(uint4*)&dst[0] = w0;
}

// ---------------- channel gram via split-bf16 MFMA ----------------
__global__ __launch_bounds__(256) void gram_kernel(
    const unsigned int* __restrict__ Kpk, const unsigned int* __restrict__ Qtn,
    float* __restrict__ Pc) {
  int bid = blockIdx.x;
  int b = bid / 100, chunk = bid % 100;
  int n0 = chunk * 64;
  int t = threadIdx.x;
  int w = t >> 6, lane = t & 63;
  int quad = lane >> 4, l16 = lane & 15;
  size_t bc = (size_t)b * CH * NPIX;

  f32x4 acc[4];
#pragma unroll
  for (int ct = 0; ct < 4; ++ct) acc[ct] = (f32x4){0.f, 0.f, 0.f, 0.f};

  // A-side (K): lane holds row w*16+l16, k-slices ks2*32 + quad*8
  const unsigned int* kp = Kpk + bc + (size_t)(w * 16 + l16) * NPIX + n0;
  bf16x8 ah[2], al[2];
#pragma unroll
  for (int ks2 = 0; ks2 < 2; ++ks2) {
    uint4 ua = *(const uint4*)&kp[ks2 * 32 + quad * 8];
    uint4 ub = *(const uint4*)&kp[ks2 * 32 + quad * 8 + 4];
    deint(ua, ub, &ah[ks2], &al[ks2]);
  }
#pragma unroll
  for (int ct = 0; ct < 4; ++ct) {
    const unsigned int* qp = Qtn + bc + (size_t)(ct * 16 + l16) * NPIX + n0;
#pragma unroll
    for (int ks2 = 0; ks2 < 2; ++ks2) {
      uint4 va = *(const uint4*)&qp[ks2 * 32 + quad * 8];
      uint4 vb = *(const uint4*)&qp[ks2 * 32 + quad * 8 + 4];
      bf16x8 bh, bl;
      deint(va, vb, &bh, &bl);
      acc[ct] = __builtin_amdgcn_mfma_f32_16x16x32_bf16(ah[ks2], bh, acc[ct], 0, 0, 0);
      acc[ct] = __builtin_amdgcn_mfma_f32_16x16x32_bf16(ah[ks2], bl, acc[ct], 0, 0, 0);
      acc[ct] = __builtin_amdgcn_mfma_f32_16x16x32_bf16(al[ks2], bh, acc[ct], 0, 0, 0);
    }
  }
#pragma unroll
  for (int ct = 0; ct < 4; ++ct)
#pragma unroll
    for (int r = 0; r < 4; ++r)
      atomicAdd(&Pc[((size_t)b * 64 + w * 16 + quad * 4 + r) * 64 + ct * 16 + l16],
                acc[ct][r]);
}

// ---------------- flash spatial attention ----------------
// v5 (bisect): v3 base + single-barrier double-buffered K/V + ESHIFT-in-C +
// setprio. psum/shfl epilogue restored (ones-MFMA dropped).
__global__ __launch_bounds__(256) void flash_kernel(
    const unsigned short* __restrict__ Qtbf, const unsigned short* __restrict__ Vbf,
    float* __restrict__ Opart, float* __restrict__ Lpart) {
  __shared__ char smem[40960] __attribute__((aligned(128)));
  // K: [2][64][64] at 0..16384; V: [2][64][64] at 16384..32768; P at 32768..40960

  int bid = blockIdx.x;
  int b = bid / 300;
  int rem = bid % 300;
  int qt = rem / 3, split = rem % 3;
  int p0 = qt * 64;
  int t = threadIdx.x;
  int w = t >> 6, lane = t & 63;
  int quad = lane >> 4, l16 = lane & 15;
  int sw = l16 & 7;
  size_t bq = (size_t)b * NPIX;
  size_t bC = (size_t)b * CH * NPIX;

  // each wave owns 16 query rows: p0 + w*16 + l16
  bf16x8 aq[2];
#pragma unroll
  for (int ks = 0; ks < 2; ++ks)
    aq[ks] = *(const bf16x8*)&Qtbf[(bq + p0 + w * 16 + l16) * 64 + ks * 32 + quad * 8];

  f32x4 oacc[4];
#pragma unroll
  for (int ct = 0; ct < 4; ++ct) oacc[ct] = (f32x4){0.f, 0.f, 0.f, 0.f};
  float psum = 0.f;

  const unsigned short* Kb = Qtbf + bq * 64;
  const unsigned short* Vb = Vbf + bC;
  int r0 = t >> 3, s0 = t & 7;  // r0 in [0,32)
  int r1 = r0 + 32;
  int wOff0 = r0 * 64 + ((s0 ^ (r0 & 7)) << 3);  // swizzled LDS dest (halves)
  int wOff1 = r1 * 64 + ((s0 ^ (r1 & 7)) << 3);

  int kt0 = split * 34;
  int niter = (split == 2) ? 32 : 34;

  unsigned short* Pw = (unsigned short*)(smem + 32768) + w * 16 * 64;

  uint4 kreg0, kreg1, vreg0, vreg1;
  {  // load tile 0
    int n0 = kt0 * 64;
    kreg0 = *(const uint4*)&Kb[(size_t)(n0 + r0) * 64 + s0 * 8];
    vreg0 = *(const uint4*)&Vb[(size_t)r0 * NPIX + n0 + s0 * 8];
    kreg1 = *(const uint4*)&Kb[(size_t)(n0 + r1) * 64 + s0 * 8];
    vreg1 = *(const uint4*)&Vb[(size_t)r1 * NPIX + n0 + s0 * 8];
  }
  {  // stage tile 0 -> buf0
    unsigned short* K0 = (unsigned short*)smem;
    unsigned short* V0 = (unsigned short*)(smem + 16384);
    *(uint4*)&K0[wOff0] = kreg0;
    *(uint4*)&V0[wOff0] = vreg0;
    *(uint4*)&K0[wOff1] = kreg1;
    *(uint4*)&V0[wOff1] = vreg1;
  }
  {  // prefetch tile 1
    int n1 = (kt0 + 1) * 64;
    kreg0 = *(const uint4*)&Kb[(size_t)(n1 + r0) * 64 + s0 * 8];
    vreg0 = *(const uint4*)&Vb[(size_t)r0 * NPIX + n1 + s0 * 8];
    kreg1 = *(const uint4*)&Kb[(size_t)(n1 + r1) * 64 + s0 * 8];
    vreg1 = *(const uint4*)&Vb[(size_t)r1 * NPIX + n1 + s0 * 8];
  }
  __syncthreads();  // buf0 ready

  for (int it = 0; it < niter; ++it) {
    int cur = it & 1;
    unsigned short* Ksc = (unsigned short*)(smem + (cur << 13));
    unsigned short* Vsc = (unsigned short*)(smem + 16384 + (cur << 13));
    // stage NEXT tile (regs hold tile it+1) into the other buffer
    if (it + 1 < niter) {
      unsigned short* Kn = (unsigned short*)(smem + ((cur ^ 1) << 13));
      unsigned short* Vn = (unsigned short*)(smem + 16384 + ((cur ^ 1) << 13));
      *(uint4*)&Kn[wOff0] = kreg0;
      *(uint4*)&Vn[wOff0] = vreg0;
      *(uint4*)&Kn[wOff1] = kreg1;
      *(uint4*)&Vn[wOff1] = vreg1;
    }
    // issue loads for tile it+2 (consumed next iter)
    if (it + 2 < niter) {
      int n2 = (kt0 + it + 2) * 64;
      kreg0 = *(const uint4*)&Kb[(size_t)(n2 + r0) * 64 + s0 * 8];
      vreg0 = *(const uint4*)&Vb[(size_t)r0 * NPIX + n2 + s0 * 8];
      kreg1 = *(const uint4*)&Kb[(size_t)(n2 + r1) * 64 + s0 * 8];
      vreg1 = *(const uint4*)&Vb[(size_t)r1 * NPIX + n2 + s0 * 8];
    }
    // S^T[k][m] with ESHIFT pre-subtracted via C-in
    f32x4 sc[4];
#pragma unroll
    for (int ct = 0; ct < 4; ++ct)
      sc[ct] = (f32x4){-ESHIFT, -ESHIFT, -ESHIFT, -ESHIFT};
    __builtin_amdgcn_s_setprio(1);
#pragma unroll
    for (int ks = 0; ks < 2; ++ks)
#pragma unroll
      for (int ct = 0; ct < 4; ++ct) {
        bf16x8 bk = *(const bf16x8*)&Ksc[(ct * 16 + l16) * 64 +
                                         (((ks * 4 + quad) ^ sw) << 3)];
        sc[ct] = __builtin_amdgcn_mfma_f32_16x16x32_bf16(bk, aq[ks], sc[ct], 0, 0, 0);
      }
    __builtin_amdgcn_s_setprio(0);
    // exp2 + pack -> P[m][k] (swizzled)
#pragma unroll
    for (int ct = 0; ct < 4; ++ct) {
      float e0 = __builtin_amdgcn_exp2f(sc[ct][0]);
      float e1 = __builtin_amdgcn_exp2f(sc[ct][1]);
      float e2 = __builtin_amdgcn_exp2f(sc[ct][2]);
      float e3 = __builtin_amdgcn_exp2f(sc[ct][3]);
      psum += (e0 + e1) + (e2 + e3);
      unsigned int pk0, pk1;
      asm("v_cvt_pk_bf16_f32 %0, %1, %2" : "=v"(pk0) : "v"(e0), "v"(e1));
      asm("v_cvt_pk_bf16_f32 %0, %1, %2" : "=v"(pk1) : "v"(e2), "v"(e3));
      uint2 pk = {pk0, pk1};
      *(uint2*)&Pw[l16 * 64 +
                   (((2 * ct + (quad >> 1)) ^ sw) << 3) + ((quad & 1) << 2)] = pk;
    }
    bf16x8 pf[2];
#pragma unroll
    for (int ks = 0; ks < 2; ++ks)
      pf[ks] = *(const bf16x8*)&Pw[l16 * 64 + (((ks * 4 + quad) ^ sw) << 3)];
    __builtin_amdgcn_s_setprio(1);
#pragma unroll
    for (int ks = 0; ks < 2; ++ks)
#pragma unroll
      for (int ct = 0; ct < 4; ++ct) {
        bf16x8 vf = *(const bf16x8*)&Vsc[(ct * 16 + l16) * 64 +
                                         (((ks * 4 + quad) ^ sw) << 3)];
        oacc[ct] = __builtin_amdgcn_mfma_f32_16x16x32_bf16(vf, pf[ks], oacc[ct], 0, 0, 0);
      }
    __builtin_amdgcn_s_setprio(0);
    __syncthreads();  // all waves done reading buf[cur]; next iter overwrites it
  }
  // epilogue: direct stores (no atomics)
  float* Op = Opart + (size_t)(split * BATCH + b) * CH * NPIX;
  int pcol = p0 + w * 16 + l16;
  {
    float s = psum;
    s += __shfl_xor(s, 16, 64);
    s += __shfl_xor(s, 32, 64);
    if (quad == 0) Lpart[(size_t)(split * BATCH + b) * NPIX + pcol] = s;
  }
#pragma unroll
  for (int ct = 0; ct < 4; ++ct)
#pragma unroll
    for (int r = 0; r < 4; ++r)
      Op[(size_t)(ct * 16 + quad * 4 + r) * NPIX + pcol] = oacc[ct][r];
}

// ---------------- finalize: out = chan_term + (sum_s Opart_s) / (sum_s Lpart_s)
__global__ __launch_bounds__(256) void finalize_kernel(
    const float* __restrict__ Pc, const unsigned short* __restrict__ Vbf,
    const float* __restrict__ Opart, const float* __restrict__ Lpart,
    float* __restrict__ out) {
  __shared__ float maT[64 * 64];  // [cp][c]
  int bid = blockIdx.x;
  int b = bid / 100, nt = bid % 100;
  int t = threadIdx.x;
  if (t < 64) {
    int c = t;
    const float* row = Pc + ((size_t)b * 64 + c) * 64;
    float v[64];
    float mx = -1e30f;
#pragma unroll
    for (int j = 0; j < 64; ++j) { v[j] = row[j]; mx = fmaxf(mx, v[j]); }
    float s = 0.f;
#pragma unroll
    for (int j = 0; j < 64; ++j) { v[j] = __expf(v[j] - mx); s += v[j]; }
    float inv = 1.f / s;
#pragma unroll
    for (int j = 0; j < 64; ++j) maT[j * 64 + c] = v[j] * inv;
  }
  __syncthreads();
  int lane = t & 63, ct = t >> 6;
  int n = nt * 64 + lane;
  size_t bc = (size_t)b * CH * NPIX;
  const unsigned short* vb = Vbf + bc + n;
  float acc[16];
#pragma unroll
  for (int j = 0; j < 16; ++j) acc[j] = 0.f;
  for (int cp = 0; cp < 64; ++cp) {
    float vv = bf2f(vb[(size_t)cp * NPIX]);
    const float* m = &maT[cp * 64 + ct * 16];
    f32x4 m0 = *(const f32x4*)&m[0];
    f32x4 m1 = *(const f32x4*)&m[4];
    f32x4 m2 = *(const f32x4*)&m[8];
    f32x4 m3 = *(const f32x4*)&m[12];
#pragma unroll
    for (int j = 0; j < 4; ++j) {
      acc[j] += m0[j] * vv;
      acc[4 + j] += m1[j] * vv;
      acc[8 + j] += m2[j] * vv;
      acc[12 + j] += m3[j] * vv;
    }
  }
  float lsum = Lpart[(size_t)(0 * BATCH + b) * NPIX + n] +
               Lpart[(size_t)(1 * BATCH + b) * NPIX + n] +
               Lpart[(size_t)(2 * BATCH + b) * NPIX + n];
  float inv = 1.f / lsum;
  const float* O0 = Opart + (size_t)(0 * BATCH + b) * CH * NPIX;
  const float* O1 = Opart + (size_t)(1 * BATCH + b) * CH * NPIX;
  const float* O2 = Opart + (size_t)(2 * BATCH + b) * CH * NPIX;
#pragma unroll
  for (int j = 0; j < 16; ++j) {
    size_t co = (size_t)(ct * 16 + j) * NPIX + n;
    float o = O0[co] + O1[co] + O2[co];
    out[bc + co] = acc[j] + o * inv;
  }
}

extern "C" void kernel_launch(void* const* d_in, const int* in_sizes, int n_in,
                              void* d_out, int out_size, void* d_ws, size_t ws_size,
                              hipStream_t stream) {
  const float* x = (const float*)d_in[0];
  const float* w = (const float*)d_in[1];
  const float* bias = (const float*)d_in[2];
  float* out = (float*)d_out;
  char* ws = (char*)d_ws;
  // layout (bytes):
  unsigned short* Qtbf = (unsigned short*)(ws);           // [0, 3276800)
  unsigned short* Vbf = (unsigned short*)(ws + 3276800);  // [3276800, 6553600)
  unsigned int* Kpk = (unsigned int*)(ws + 6553600);      // [6553600, 13107200) dead after gram
  unsigned int* Qtn = (unsigned int*)(ws + 13107200);     // [13107200, 19660800) dead after gram
  float* Opart = (float*)(ws + 6553600);                  // [6553600, 26214400) 3 splits, after gram
  float* Pc = (float*)(ws + 26214400);                    // [26214400, 26279936)
  float* Lpart = (float*)(ws + 26279936);                 // [26279936, 26587136)

  hipMemsetAsync(Pc, 0, 65536, stream);
  qkv_kernel<<<400, 512, 0, stream>>>(x, w, bias, Qtbf, Vbf, Kpk, Qtn);
  gram_kernel<<<400, 256, 0, stream>>>(Kpk, Qtn, Pc);
  flash_kernel<<<1200, 256, 0, stream>>>(Qtbf, Vbf, Opart, Lpart);
  finalize_kernel<<<400, 256, 0, stream>>>(Pc, Vbf, Opart, Lpart, out);
}